// Round 10
// baseline (224.267 us; speedup 1.0000x reference)
//
#include <hip/hip_runtime.h>
#include <hip/hip_bf16.h>
#include <math.h>

#define Bb 8
#define Ss 1024
#define Ee 768
#define Hh 12
#define Mm (Bb*Ss)      // 8192 rows
#define NW (Ee*Ee)      // 589824
#define LQKV 2304       // fused QKV row stride (u16 elements)

typedef short  s16x8 __attribute__((ext_vector_type(8)));   // 8 bf16 (4 VGPRs)
typedef float  f32x4 __attribute__((ext_vector_type(4)));

#define FENCE() __builtin_amdgcn_sched_barrier(0)
#define BAR_ONLY() do { FENCE(); __builtin_amdgcn_s_barrier(); FENCE(); } while(0)
#define BAR_LGKM() do { FENCE(); asm volatile("s_waitcnt lgkmcnt(0)" ::: "memory"); FENCE(); \
                        __builtin_amdgcn_s_barrier(); FENCE(); } while(0)

__device__ __forceinline__ void gload_lds16(const void* g, void* l) {
    __builtin_amdgcn_global_load_lds(
        (const __attribute__((address_space(1))) void*)g,
        (__attribute__((address_space(3))) void*)l, 16, 0, 0);
}

__device__ __forceinline__ unsigned short f2bf(float f) {
    __hip_bfloat16 b = __float2bfloat16(f);   // RNE
    return *reinterpret_cast<unsigned short*>(&b);
}
__device__ __forceinline__ float bf2f(unsigned short h) {
    return __uint_as_float(((unsigned)h) << 16);
}

// ---------------- block-wide sum over 256 threads ----------------
__device__ __forceinline__ float block_sum_256(float v, float* red) {
    #pragma unroll
    for (int off = 32; off > 0; off >>= 1) v += __shfl_down(v, off, 64);
    __syncthreads();
    if ((threadIdx.x & 63) == 0) red[threadIdx.x >> 6] = v;
    __syncthreads();
    return red[0] + red[1] + red[2] + red[3];
}

// ---------------- fused: x->bf16 + row norm  |  weights->bf16 ----------------
__global__ __launch_bounds__(256) void pack_xw_kernel(const float* __restrict__ x,
    const float* __restrict__ W0, const float* __restrict__ W1,
    const float* __restrict__ W2, const float* __restrict__ W3,
    unsigned short* __restrict__ Xb, float* __restrict__ xn,
    unsigned short* __restrict__ Wb) {
    __shared__ float red[4];
    const int bid = blockIdx.x;
    if (bid < Mm) {
        size_t row = bid;
        const float* a = x + row * Ee;
        float ssum = 0.f;
        #pragma unroll
        for (int l = 0; l < 3; ++l) {
            float v = a[threadIdx.x + l*256];
            ssum += v*v;
            Xb[row*Ee + threadIdx.x + l*256] = f2bf(v);
        }
        float tot = block_sum_256(ssum, red);
        if (threadIdx.x == 0) xn[row] = fmaxf(sqrtf(tot), 1e-15f);
    } else {
        int idx = bid - Mm;
        const int perW = NW/1024;          // 576
        int which = idx / perW;
        int chunk = idx - which*perW;
        const float* src = (which == 0) ? W0 : (which == 1) ? W1 : (which == 2) ? W2 : W3;
        size_t off = (size_t)chunk * 1024 + threadIdx.x * 4;
        float4 v = *reinterpret_cast<const float4*>(&src[off]);
        uint2 o;
        o.x = (unsigned)f2bf(v.x) | ((unsigned)f2bf(v.y) << 16);
        o.y = (unsigned)f2bf(v.z) | ((unsigned)f2bf(v.w) << 16);
        *reinterpret_cast<uint2*>(Wb + (size_t)which * NW + off) = o;
    }
}

// ---------------- C[M,N] = A[M,768](bf16,lda) @ B[N,768](bf16)^T ----------------
// m97 structure: BM=BN=128, BK=64; global_load_lds w16 staging; linear LDS;
// single-buffer 2-barrier loop; 1D grid with bijective XCD swizzle.
template<int OUT16>
__global__ __launch_bounds__(256) void gemm_bf16_nt(const unsigned short* __restrict__ A,
                                                    int lda,
                                                    const unsigned short* __restrict__ B,
                                                    void* __restrict__ Cout, int ldc,
                                                    int mtiles) {
    __shared__ alignas(16) unsigned short As[128][64];   // 16KB linear
    __shared__ alignas(16) unsigned short Bs[128][64];   // 16KB linear
    const int tid = threadIdx.x, lane = tid & 63, w = tid >> 6;
    const int g = lane >> 4, lg = lane & 15;
    // bijective XCD swizzle (gridDim.x % 8 == 0): XCD-contiguous blocks share B-panel
    const int cpx = gridDim.x >> 3;
    const int swz = (blockIdx.x & 7) * cpx + (blockIdx.x >> 3);
    const int mBase = (swz % mtiles) * 128, nBase = (swz / mtiles) * 128;
    const int wr = w >> 1, wc = w & 1;
    const int sr8 = lane >> 3;               // 0..7 row-in-8 for staging source
    const int scol = (lane & 7) * 8;         // staging col (u16)
    f32x4 zero4 = {0.f,0.f,0.f,0.f};
    f32x4 acc[4][4];
    #pragma unroll
    for (int i = 0; i < 4; ++i)
        #pragma unroll
        for (int j = 0; j < 4; ++j) acc[i][j] = zero4;

    for (int k0 = 0; k0 < Ee; k0 += 64) {
        // stage A & B tiles: 4+4 wave-deposits of 1KB (64 lanes x 16B), linear LDS
        #pragma unroll
        for (int i = 0; i < 4; ++i) {
            const int r0 = w*32 + i*8;       // wave-uniform LDS row base
            gload_lds16(&A[(size_t)(mBase + r0 + sr8)*lda + k0 + scol], &As[r0][0]);
            gload_lds16(&B[(size_t)(nBase + r0 + sr8)*Ee  + k0 + scol], &Bs[r0][0]);
        }
        FENCE();
        asm volatile("s_waitcnt vmcnt(0)" ::: "memory");
        FENCE();
        __builtin_amdgcn_s_barrier();        // all deposits visible
        #pragma unroll
        for (int kk = 0; kk < 2; ++kk) {
            s16x8 af[4], bfr[4];
            #pragma unroll
            for (int mi = 0; mi < 4; ++mi)
                af[mi] = *(const s16x8*)&As[wr*64 + mi*16 + lg][(kk*4 + g)*8];
            #pragma unroll
            for (int ni = 0; ni < 4; ++ni)
                bfr[ni] = *(const s16x8*)&Bs[wc*64 + ni*16 + lg][(kk*4 + g)*8];
            #pragma unroll
            for (int mi = 0; mi < 4; ++mi)
                #pragma unroll
                for (int ni = 0; ni < 4; ++ni)
                    acc[mi][ni] = __builtin_amdgcn_mfma_f32_16x16x32_bf16(af[mi], bfr[ni], acc[mi][ni], 0, 0, 0);
        }
        BAR_LGKM();                          // reads done before next stage overwrites
    }
    #pragma unroll
    for (int mi = 0; mi < 4; ++mi)
        #pragma unroll
        for (int ni = 0; ni < 4; ++ni)
            #pragma unroll
            for (int r = 0; r < 4; ++r) {
                size_t off = (size_t)(mBase + wr*64 + mi*16 + g*4 + r)*ldc + nBase + wc*64 + ni*16 + lg;
                if (OUT16) ((unsigned short*)Cout)[off] = f2bf(acc[mi][ni][r]);
                else       ((float*)Cout)[off] = acc[mi][ni][r];
            }
}

// ---------------- fused mobius fix for Q/K/V, in-place bf16, + per-head info ----------------
__global__ __launch_bounds__(256) void fix_qkv_kernel(unsigned short* __restrict__ QKV,
                                                      const float* __restrict__ xn_buf,
                                                      const float* __restrict__ bq,
                                                      const float* __restrict__ bk,
                                                      const float* __restrict__ bv_,
                                                      float2* __restrict__ qinfo,
                                                      float2* __restrict__ kinfo) {
    __shared__ float red[4], red2[4];
    const int which = blockIdx.y;
    size_t row = blockIdx.x;
    const int tid = threadIdx.x;
    const float* bias = (which == 0) ? bq : (which == 1) ? bk : bv_;
    unsigned short* m = QKV + row * LQKV + which * Ee;
    float mv[3], bv[3];
    float ss = 0.f;
    #pragma unroll
    for (int l = 0; l < 3; ++l) { mv[l] = bf2f(m[tid + l*256]); ss += mv[l]*mv[l]; }
    float mxn2 = block_sum_256(ss, red);
    float mxn = fmaxf(sqrtf(mxn2), 1e-15f);
    float xn = xn_buf[row];
    float xc = fminf(xn, 1.f - 1e-7f);
    float at = 0.5f * logf((1.f + xc) / (1.f - xc));
    float th = tanhf(mxn / xn * at);
    float scale = th / mxn;
    float m2 = th * th;
    float mb = 0.f, b2 = 0.f;
    #pragma unroll
    for (int l = 0; l < 3; ++l) {
        bv[l] = bias[tid + l*256];
        mv[l] *= scale;
        mb += mv[l]*bv[l];
        b2 += bv[l]*bv[l];
    }
    mb = block_sum_256(mb, red);
    b2 = block_sum_256(b2, red2);
    float ncoef = 1.f + 2.f*mb + b2;
    float bcoef = 1.f - m2;
    float inv = 1.f / (1.f + 2.f*mb + m2*b2 + 1e-15f);
    const int lane = tid & 63, wv = tid >> 6;
    if (which < 2) {
        #pragma unroll
        for (int l = 0; l < 3; ++l) {
            float f = (ncoef*mv[l] + bcoef*bv[l]) * inv;
            float c = fminf(f, 1.f - 1e-5f);
            m[tid + l*256] = f2bf(c);
            float s2 = c*c;
            #pragma unroll
            for (int off = 1; off < 64; off <<= 1) s2 += __shfl_xor(s2, off);
            if (lane == 0) {
                if (which == 0)
                    qinfo[(size_t)(wv + 4*l)*Mm + row] = make_float2(2.f*s2, 1.f/(1.f - s2));
                else {
                    float ik = 1.f/(1.f - s2);
                    kinfo[(size_t)(wv + 4*l)*Mm + row] = make_float2(ik, 2.f*s2*ik);
                }
            }
        }
    } else {
        #pragma unroll
        for (int l = 0; l < 3; ++l)
            m[tid + l*256] = f2bf((ncoef*mv[l] + bcoef*bv[l]) * inv);
    }
}

// ---------------- V transpose (bf16 -> bf16): qkv v-region -> [b,h,d][1024] ----------------
__global__ __launch_bounds__(256) void transpose_v_kernel(const unsigned short* __restrict__ QKV,
                                                          unsigned short* __restrict__ Vb) {
    __shared__ unsigned short t[64][72];
    const int tid = threadIdx.x;
    const int st = blockIdx.x, h = blockIdx.y, b = blockIdx.z;
    {
        int sr = tid >> 2, d0 = (tid & 3) * 16;
        const unsigned short* vp = QKV + ((size_t)b*Ss + st*64 + sr)*LQKV + 2*Ee + h*64 + d0;
        *(s16x8*)&t[sr][d0]     = *(const s16x8*)&vp[0];
        *(s16x8*)&t[sr][d0 + 8] = *(const s16x8*)&vp[8];
    }
    __syncthreads();
    {
        int d = tid >> 2, s0 = (tid & 3) * 16;
        unsigned hu[8];
        #pragma unroll
        for (int i = 0; i < 8; ++i)
            hu[i] = (unsigned)t[s0 + 2*i][d] | ((unsigned)t[s0 + 2*i + 1][d] << 16);
        size_t obase = (((size_t)b*Hh + h)*64 + d)*Ss + st*64 + s0;
        *reinterpret_cast<uint4*>(&Vb[obase])     = make_uint4(hu[0],hu[1],hu[2],hu[3]);
        *reinterpret_cast<uint4*>(&Vb[obase + 8]) = make_uint4(hu[4],hu[5],hu[6],hu[7]);
    }
}

// ---------------- MFMA attention: 128 q-rows/block (32/wave), scalar transform ----------------
__global__ __launch_bounds__(256) void attn_mfma5(
    unsigned short* __restrict__ QKV, const unsigned short* __restrict__ Vb,
    const float2* __restrict__ qinfo, const float2* __restrict__ kinfo,
    const float* __restrict__ hs, float* __restrict__ osq)
{
    __shared__ alignas(16) unsigned short KHs[2][64][64];    // 16KB
    __shared__ alignas(16) unsigned short VHs[2][64][64];    // 16KB
    __shared__ alignas(16) unsigned short PHs[4][2][16][64]; // 16KB
    __shared__ float us[2][64], vs[2][64];                   // 1KB

    const int tid = threadIdx.x, lane = tid & 63, w = tid >> 6;
    const int g = lane >> 4, lg = lane & 15;
    const int qt = blockIdx.x, h = blockIdx.y, b = blockIdx.z;
    const int q0 = qt * 128, hoff = h * 64;
    const size_t rowB = (size_t)b * Ss;
    const size_t hMm = (size_t)h * Mm;
    const size_t vBase = (((size_t)b*Hh + h)*64)*Ss;
    const int rr = tid >> 3, cc = tid & 7;
    const int csw = (cc ^ (rr & 7)) * 8;    // same for rr and rr+32

    const unsigned short* kgp = &QKV[(rowB + rr)*LQKV + Ee + hoff + cc*8];
    const unsigned short* vgp = &Vb[vBase + (size_t)rr*Ss + cc*8];

    // Q fragments + per-q constants (2 row-groups of 16 per wave)
    s16x8 qh[2][2];
    float a2s[2], ioms[2];
    #pragma unroll
    for (int qi = 0; qi < 2; ++qi) {
        const unsigned short* qp = QKV + (rowB + q0 + 32*w + qi*16 + lg)*LQKV + hoff;
        qh[qi][0] = *(const s16x8*)&qp[g*8];
        qh[qi][1] = *(const s16x8*)&qp[32 + g*8];
        float2 qiv = qinfo[hMm + rowB + q0 + 32*w + qi*16 + lg];
        a2s[qi] = qiv.x;
        ioms[qi] = qiv.y;
    }
    const float nia = -1.f / (hs[h] * 8.f);   // p = uu^nia

    s16x8 cka, ckb, cva, cvb, nka, nkb, nva, nvb;
    #define LOADKV(ka,kb,va,vb_,kt) do { \
        ka  = *(const s16x8*)&kgp[(size_t)(kt)*64*LQKV]; \
        kb  = *(const s16x8*)&kgp[(size_t)(kt)*64*LQKV + (size_t)32*LQKV]; \
        va  = *(const s16x8*)&vgp[(kt)*64]; \
        vb_ = *(const s16x8*)&vgp[(size_t)32*Ss + (kt)*64]; } while(0)
    #define WRITEKV(bi,ka,kb,va,vb_) do { \
        *(s16x8*)&KHs[bi][rr     ][csw] = ka; \
        *(s16x8*)&KHs[bi][rr + 32][csw] = kb; \
        *(s16x8*)&VHs[bi][rr     ][csw] = va; \
        *(s16x8*)&VHs[bi][rr + 32][csw] = vb_; } while(0)

    LOADKV(cka,ckb,cva,cvb, 0);
    LOADKV(nka,nkb,nva,nvb, 1);
    float2 uvC = make_float2(0.f,0.f), uvN = make_float2(0.f,0.f);
    if (tid < 64) uvC = kinfo[hMm + rowB + tid];
    if (tid < 64) uvN = kinfo[hMm + rowB + 64 + tid];
    WRITEKV(0, cka,ckb,cva,cvb);
    if (tid < 64) { us[0][tid] = uvC.x; vs[0][tid] = uvC.y; }
    BAR_LGKM();

    f32x4 zero4 = {0.f,0.f,0.f,0.f};
    f32x4 oacc[2][4];
    #pragma unroll
    for (int qi = 0; qi < 2; ++qi)
        #pragma unroll
        for (int i = 0; i < 4; ++i) oacc[qi][i] = zero4;
    float lsum0 = 0.f, lsum1 = 0.f;
    int cur = 0;

    for (int kt = 0; kt < 16; ++kt) {
        if (kt < 15) {
            WRITEKV(cur^1, nka,nkb,nva,nvb);
            if (tid < 64) { us[cur^1][tid] = uvN.x; vs[cur^1][tid] = uvN.y; }
        }
        if (kt < 14) {
            LOADKV(nka,nkb,nva,nvb, kt+2);
            if (tid < 64) uvN = kinfo[hMm + rowB + (kt+2)*64 + tid];
        }

        // ---- S^T tile = K · Q^T (each K-frag feeds 2 q-groups) ----
        f32x4 sacc[2][4];
        #pragma unroll
        for (int qi = 0; qi < 2; ++qi)
            #pragma unroll
            for (int i = 0; i < 4; ++i) sacc[qi][i] = zero4;
        __builtin_amdgcn_s_setprio(1);
        #pragma unroll
        for (int nt = 0; nt < 4; ++nt) {
            const int krow = nt*16 + lg, sw = krow & 7;
            s16x8 kh0 = *(const s16x8*)&KHs[cur][krow][((g    ) ^ sw)*8];
            s16x8 kh1 = *(const s16x8*)&KHs[cur][krow][((4 + g) ^ sw)*8];
            sacc[0][nt] = __builtin_amdgcn_mfma_f32_16x16x32_bf16(kh0, qh[0][0], sacc[0][nt], 0, 0, 0);
            sacc[0][nt] = __builtin_amdgcn_mfma_f32_16x16x32_bf16(kh1, qh[0][1], sacc[0][nt], 0, 0, 0);
            sacc[1][nt] = __builtin_amdgcn_mfma_f32_16x16x32_bf16(kh0, qh[1][0], sacc[1][nt], 0, 0, 0);
            sacc[1][nt] = __builtin_amdgcn_mfma_f32_16x16x32_bf16(kh1, qh[1][1], sacc[1][nt], 0, 0, 0);
        }
        __builtin_amdgcn_s_setprio(0);

        // ---- hyperbolic transform (scalar fp32) -> unnormalized P (bf16) ----
        #pragma unroll
        for (int nt = 0; nt < 4; ++nt) {
            const int j0 = nt*16 + g*4;
            float4 uq4 = *reinterpret_cast<const float4*>(&us[cur][j0]);
            float4 vq4 = *reinterpret_cast<const float4*>(&vs[cur][j0]);
            float uqa[4] = {uq4.x, uq4.y, uq4.z, uq4.w};
            float vqa[4] = {vq4.x, vq4.y, vq4.z, vq4.w};
            const int chq = ((j0 >> 3) ^ (lg & 7))*8 + (j0 & 7);
            #pragma unroll
            for (int qi = 0; qi < 2; ++qi) {
                float pr[4];
                #pragma unroll
                for (int r = 0; r < 4; ++r) {
                    float s  = sacc[qi][nt][r];
                    float wv = fmaf(-4.f, s, a2s[qi]);                  // 2q2 - 4s
                    float z  = fmaf(ioms[qi], fmaf(uqa[r], wv, vqa[r]), 1.f);  // 1 + t
                    z = fmaxf(z, 1.f);
                    float sq = __builtin_amdgcn_sqrtf(fmaf(z, z, -1.f));       // sqrt(z^2-1)
                    float uu = z + sq;                                  // arccosh arg
                    float p  = __builtin_amdgcn_exp2f(nia * __builtin_amdgcn_logf(uu));
                    if (qi == 0) lsum0 += p; else lsum1 += p;
                    pr[r] = p;
                }
                unsigned p01, p23;
                asm("v_cvt_pk_bf16_f32 %0, %1, %2" : "=v"(p01) : "v"(pr[0]), "v"(pr[1]));
                asm("v_cvt_pk_bf16_f32 %0, %1, %2" : "=v"(p23) : "v"(pr[2]), "v"(pr[3]));
                *reinterpret_cast<uint2*>(&PHs[w][qi][lg][chq]) = make_uint2(p01, p23);
            }
        }

        // ---- O += P · V (each V-frag feeds 2 q-groups; P wave-private) ----
        __builtin_amdgcn_s_setprio(1);
        #pragma unroll
        for (int jh = 0; jh < 2; ++jh) {
            s16x8 pa0 = *(const s16x8*)&PHs[w][0][lg][((jh*4 + g) ^ (lg & 7))*8];
            s16x8 pa1 = *(const s16x8*)&PHs[w][1][lg][((jh*4 + g) ^ (lg & 7))*8];
            #pragma unroll
            for (int nt2 = 0; nt2 < 4; ++nt2) {
                const int vrow = nt2*16 + lg;
                s16x8 vh = *(const s16x8*)&VHs[cur][vrow][((jh*4 + g) ^ (vrow & 7))*8];
                oacc[0][nt2] = __builtin_amdgcn_mfma_f32_16x16x32_bf16(pa0, vh, oacc[0][nt2], 0, 0, 0);
                oacc[1][nt2] = __builtin_amdgcn_mfma_f32_16x16x32_bf16(pa1, vh, oacc[1][nt2], 0, 0, 0);
            }
        }
        __builtin_amdgcn_s_setprio(0);

        BAR_LGKM();
        cur ^= 1;
    }
    #undef LOADKV
    #undef WRITEKV

    // ---- normalize, store bf16 O, per-row sumsq ----
    #pragma unroll
    for (int qi = 0; qi < 2; ++qi) {
        float ls = (qi == 0) ? lsum0 : lsum1;
        ls += __shfl_xor(ls, 16);
        ls += __shfl_xor(ls, 32);
        #pragma unroll
        for (int r = 0; r < 4; ++r) {
            float lr = __shfl(ls, g*4 + r, 64);
            float li = 1.f / lr;
            float sq = 0.f;
            const size_t orow = rowB + q0 + 32*w + qi*16 + g*4 + r;
            #pragma unroll
            for (int nt2 = 0; nt2 < 4; ++nt2) {
                float o = oacc[qi][nt2][r] * li;
                sq = fmaf(o, o, sq);
                QKV[orow*LQKV + 2*Ee + hoff + nt2*16 + lg] = f2bf(o);
            }
            sq += __shfl_xor(sq, 1);
            sq += __shfl_xor(sq, 2);
            sq += __shfl_xor(sq, 4);
            sq += __shfl_xor(sq, 8);
            if (lg == 0) osq[hMm + orow] = sq;
        }
    }
}

// ---------------- final mobius fix: xn = sqrt(sum_h osq) ----------------
__global__ __launch_bounds__(256) void mobius_fix_final(const float* __restrict__ src,
                                                        float* __restrict__ dst,
                                                        const float* __restrict__ osq,
                                                        const float* __restrict__ bias) {
    __shared__ float red[4], red2[4];
    size_t row = blockIdx.x;
    const float* m = src + row * Ee;
    float mv[3], bv[3];
    float ss = 0.f;
    #pragma unroll
    for (int l = 0; l < 3; ++l) { mv[l] = m[threadIdx.x + l*256]; ss += mv[l]*mv[l]; }
    float mxn2 = block_sum_256(ss, red);
    float mxn = fmaxf(sqrtf(mxn2), 1e-15f);
    float ss2 = 0.f;
    #pragma unroll
    for (int hh = 0; hh < Hh; ++hh) ss2 += osq[(size_t)hh*Mm + row];
    float xn = fmaxf(sqrtf(ss2), 1e-15f);
    float xc = fminf(xn, 1.f - 1e-7f);
    float at = 0.5f * logf((1.f + xc) / (1.f - xc));
    float th = tanhf(mxn / xn * at);
    float scale = th / mxn;
    float m2 = th * th;
    float mb = 0.f, b2 = 0.f;
    #pragma unroll
    for (int l = 0; l < 3; ++l) {
        bv[l] = bias[threadIdx.x + l*256];
        mv[l] *= scale;
        mb += mv[l]*bv[l];
        b2 += bv[l]*bv[l];
    }
    mb = block_sum_256(mb, red);
    b2 = block_sum_256(b2, red2);
    float ncoef = 1.f + 2.f*mb + b2;
    float bcoef = 1.f - m2;
    float inv = 1.f / (1.f + 2.f*mb + m2*b2 + 1e-15f);
    float* d = dst + row * Ee;
    #pragma unroll
    for (int l = 0; l < 3; ++l)
        d[threadIdx.x + l*256] = (ncoef*mv[l] + bcoef*bv[l]) * inv;
}

extern "C" void kernel_launch(void* const* d_in, const int* in_sizes, int n_in,
                              void* d_out, int out_size, void* d_ws, size_t ws_size,
                              hipStream_t stream) {
    const float* x  = (const float*)d_in[0];
    const float* Wq = (const float*)d_in[1];
    const float* bq = (const float*)d_in[2];
    const float* Wk = (const float*)d_in[3];
    const float* bk = (const float*)d_in[4];
    const float* Wv = (const float*)d_in[5];
    const float* bv = (const float*)d_in[6];
    const float* Wo = (const float*)d_in[7];
    const float* bo = (const float*)d_in[8];
    const float* hs = (const float*)d_in[9];
    float* out = (float*)d_out;

    const size_t NE = (size_t)Mm * Ee;
    float* ws    = (float*)d_ws;
    float* xn_x  = ws;                                   // Mm f32
    float* osq   = xn_x + Mm;                            // Hh*Mm f32
    float2* qinfo = (float2*)(osq + (size_t)Hh*Mm);      // Hh*Mm f32x2
    float2* kinfo = qinfo + (size_t)Hh*Mm;               // Hh*Mm f32x2
    unsigned short* qkvbf = (unsigned short*)(kinfo + (size_t)Hh*Mm);  // Mm*2304 u16
    unsigned short* vtbf  = qkvbf + (size_t)Mm * LQKV;   // NE u16
    unsigned short* xbf   = vtbf + NE;                   // NE u16
    unsigned short* wbf   = xbf + NE;                    // 4*NW u16
    float* fbuf = (float*)vtbf;   // fp32 [Mm][768] overlays vtbf+xbf (dead by then)

    pack_xw_kernel<<<Mm + 4*(NW/1024), 256, 0, stream>>>(x, Wq, Wk, Wv, Wo, xbf, xn_x, wbf);

    // fused QKV projection -> bf16 [Mm][2304]; 1152 blocks (%8==0), XCD-swizzled
    gemm_bf16_nt<1><<<(Mm/128)*(LQKV/128), 256, 0, stream>>>(xbf, Ee, wbf, qkvbf, LQKV, Mm/128);
    fix_qkv_kernel<<<dim3(Mm, 3), 256, 0, stream>>>(qkvbf, xn_x, bq, bk, bv, qinfo, kinfo);
    transpose_v_kernel<<<dim3(Ss/64, Hh, Bb), 256, 0, stream>>>(qkvbf, vtbf);

    // attention: O (bf16) overwrites V region; osq = per-(head,row) sumsq
    attn_mfma5<<<dim3(Ss/128, Hh, Bb), 256, 0, stream>>>(qkvbf, vtbf, qinfo, kinfo, hs, osq);

    // output projection; 384 blocks (%8==0), XCD-swizzled
    gemm_bf16_nt<0><<<(Mm/128)*(Ee/128), 256, 0, stream>>>(qkvbf + 2*Ee, LQKV, wbf + 3*(size_t)NW, fbuf, Ee, Mm/128);
    mobius_fix_final<<<Mm, 256, 0, stream>>>(fbuf, out, osq, bo);
}

// Round 11
// 181.418 us; speedup vs baseline: 1.2362x; 1.2362x over previous
//
#include <hip/hip_runtime.h>
#include <hip/hip_bf16.h>
#include <math.h>

#define Bb 8
#define Ss 1024
#define Ee 768
#define Hh 12
#define Mm (Bb*Ss)      // 8192 rows
#define NW (Ee*Ee)      // 589824
#define LQKV 2304       // fused QKV row stride (u16 elements)

typedef short  s16x8 __attribute__((ext_vector_type(8)));   // 8 bf16 (4 VGPRs)
typedef float  f32x4 __attribute__((ext_vector_type(4)));

#define FENCE() __builtin_amdgcn_sched_barrier(0)
#define BAR_ONLY() do { FENCE(); __builtin_amdgcn_s_barrier(); FENCE(); } while(0)
#define BAR_LGKM() do { FENCE(); asm volatile("s_waitcnt lgkmcnt(0)" ::: "memory"); FENCE(); \
                        __builtin_amdgcn_s_barrier(); FENCE(); } while(0)

__device__ __forceinline__ unsigned short f2bf(float f) {
    __hip_bfloat16 b = __float2bfloat16(f);   // RNE
    return *reinterpret_cast<unsigned short*>(&b);
}
__device__ __forceinline__ float bf2f(unsigned short h) {
    return __uint_as_float(((unsigned)h) << 16);
}
__device__ __forceinline__ float wave_sum(float v) {
    #pragma unroll
    for (int off = 1; off < 64; off <<= 1) v += __shfl_xor(v, off);
    return v;
}

// ---------------- fused: x->bf16 + row norm (wave/row) | weights->bf16 ----------------
__global__ __launch_bounds__(256) void pack_xw_kernel(const float* __restrict__ x,
    const float* __restrict__ W0, const float* __restrict__ W1,
    const float* __restrict__ W2, const float* __restrict__ W3,
    unsigned short* __restrict__ Xb, float* __restrict__ xn,
    unsigned short* __restrict__ Wb) {
    const int bid = blockIdx.x;
    const int lane = threadIdx.x & 63, wv = threadIdx.x >> 6;
    if (bid < Mm/4) {
        size_t row = (size_t)bid * 4 + wv;
        const float* a = x + row * Ee;
        float ssum = 0.f;
        #pragma unroll
        for (int l = 0; l < 12; ++l) {
            float v = a[lane + l*64];
            ssum += v*v;
            Xb[row*Ee + lane + l*64] = f2bf(v);
        }
        ssum = wave_sum(ssum);
        if (lane == 0) xn[row] = fmaxf(sqrtf(ssum), 1e-15f);
    } else {
        int idx = bid - Mm/4;
        const int perW = NW/1024;          // 576
        int which = idx / perW;
        int chunk = idx - which*perW;
        const float* src = (which == 0) ? W0 : (which == 1) ? W1 : (which == 2) ? W2 : W3;
        size_t off = (size_t)chunk * 1024 + threadIdx.x * 4;
        float4 v = *reinterpret_cast<const float4*>(&src[off]);
        uint2 o;
        o.x = (unsigned)f2bf(v.x) | ((unsigned)f2bf(v.y) << 16);
        o.y = (unsigned)f2bf(v.z) | ((unsigned)f2bf(v.w) << 16);
        *reinterpret_cast<uint2*>(Wb + (size_t)which * NW + off) = o;
    }
}

// ---------------- C[M,N] = A[M,768](bf16,lda) @ B[N,768](bf16)^T ----------------
// BM=128, BN=128, BK=64; 256 threads; reg-staged 2-phase, raw barriers (R8-proven).
template<int OUT16>
__global__ __launch_bounds__(256) void gemm_bf16_nt(const unsigned short* __restrict__ A,
                                                    int lda,
                                                    const unsigned short* __restrict__ B,
                                                    void* __restrict__ Cout, int ldc) {
    __shared__ alignas(16) unsigned short As[128][64];   // 16KB, chunk-XOR-swizzled
    __shared__ alignas(16) unsigned short Bs[128][64];   // 16KB
    const int tid = threadIdx.x, lane = tid & 63, w = tid >> 6;
    const int g = lane >> 4, lg = lane & 15;
    const int mBase = blockIdx.x * 128, nBase = blockIdx.y * 128;
    const int wr = w >> 1, wc = w & 1;
    const int rr = tid >> 3, cc = tid & 7;
    const int csw = (cc ^ (rr & 7)) * 8;   // same for rr+32k (32 ≡ 0 mod 8)
    f32x4 zero4 = {0.f,0.f,0.f,0.f};
    f32x4 acc[4][4];
    #pragma unroll
    for (int i = 0; i < 4; ++i)
        #pragma unroll
        for (int j = 0; j < 4; ++j) acc[i][j] = zero4;

    s16x8 av[4], bv[4];
    #define GLOAD(k0) do { \
        _Pragma("unroll") \
        for (int i = 0; i < 4; ++i) { \
            av[i] = *(const s16x8*)&A[(size_t)(mBase + rr + i*32)*lda + (k0) + cc*8]; \
            bv[i] = *(const s16x8*)&B[(size_t)(nBase + rr + i*32)*Ee  + (k0) + cc*8]; \
        } } while(0)

    GLOAD(0);
    for (int k0 = 0; k0 < Ee; k0 += 64) {
        BAR_ONLY();                        // prev compute consumed its reads pre-barrier
        #pragma unroll
        for (int i = 0; i < 4; ++i) {
            *(s16x8*)&As[rr + i*32][csw] = av[i];
            *(s16x8*)&Bs[rr + i*32][csw] = bv[i];
        }
        if (k0 + 64 < Ee) GLOAD(k0 + 64);  // stays in flight across the barrier
        BAR_LGKM();                        // LDS visible; vmcnt NOT drained
        __builtin_amdgcn_s_setprio(1);
        #pragma unroll
        for (int kk = 0; kk < 2; ++kk) {
            s16x8 af[4], bfr[4];
            #pragma unroll
            for (int mi = 0; mi < 4; ++mi) {
                int ar = wr*64 + mi*16 + lg;
                af[mi] = *(const s16x8*)&As[ar][(((kk*4 + g) ^ (ar & 7)))*8];
            }
            #pragma unroll
            for (int ni = 0; ni < 4; ++ni) {
                int br = wc*64 + ni*16 + lg;
                bfr[ni] = *(const s16x8*)&Bs[br][(((kk*4 + g) ^ (br & 7)))*8];
            }
            #pragma unroll
            for (int mi = 0; mi < 4; ++mi)
                #pragma unroll
                for (int ni = 0; ni < 4; ++ni)
                    acc[mi][ni] = __builtin_amdgcn_mfma_f32_16x16x32_bf16(af[mi], bfr[ni], acc[mi][ni], 0, 0, 0);
        }
        __builtin_amdgcn_s_setprio(0);
    }
    #undef GLOAD
    #pragma unroll
    for (int mi = 0; mi < 4; ++mi)
        #pragma unroll
        for (int ni = 0; ni < 4; ++ni)
            #pragma unroll
            for (int r = 0; r < 4; ++r) {
                size_t off = (size_t)(mBase + wr*64 + mi*16 + g*4 + r)*ldc + nBase + wc*64 + ni*16 + lg;
                if (OUT16) ((unsigned short*)Cout)[off] = f2bf(acc[mi][ni][r]);
                else       ((float*)Cout)[off] = acc[mi][ni][r];
            }
}

// ---------------- mobius fix Q/K/V (wave/row, no barriers), in-place bf16 + per-head info ----------------
// grid (Mm/4, 3); elem index = l*64 + lane -> head == l (per-head reduce is free)
__global__ __launch_bounds__(256) void fix_qkv_kernel(unsigned short* __restrict__ QKV,
                                                      const float* __restrict__ xn_buf,
                                                      const float* __restrict__ bq,
                                                      const float* __restrict__ bk,
                                                      const float* __restrict__ bv_,
                                                      float2* __restrict__ qinfo,
                                                      float2* __restrict__ kinfo) {
    const int which = blockIdx.y;
    const int lane = threadIdx.x & 63, wv = threadIdx.x >> 6;
    size_t row = (size_t)blockIdx.x * 4 + wv;
    const float* bias = (which == 0) ? bq : (which == 1) ? bk : bv_;
    unsigned short* m = QKV + row * LQKV + which * Ee;
    float mv[12], bv[12];
    float ss = 0.f;
    #pragma unroll
    for (int l = 0; l < 12; ++l) { mv[l] = bf2f(m[lane + l*64]); ss += mv[l]*mv[l]; }
    float mxn2 = wave_sum(ss);
    float mxn = fmaxf(sqrtf(mxn2), 1e-15f);
    float xn = xn_buf[row];
    float xc = fminf(xn, 1.f - 1e-7f);
    float at = 0.5f * logf((1.f + xc) / (1.f - xc));
    float th = tanhf(mxn / xn * at);
    float scale = th / mxn;
    float m2 = th * th;
    float mb = 0.f, b2 = 0.f;
    #pragma unroll
    for (int l = 0; l < 12; ++l) {
        bv[l] = bias[lane + l*64];
        mv[l] *= scale;
        mb += mv[l]*bv[l];
        b2 += bv[l]*bv[l];
    }
    mb = wave_sum(mb);
    b2 = wave_sum(b2);
    float ncoef = 1.f + 2.f*mb + b2;
    float bcoef = 1.f - m2;
    float inv = 1.f / (1.f + 2.f*mb + m2*b2 + 1e-15f);
    if (which < 2) {
        #pragma unroll
        for (int l = 0; l < 12; ++l) {
            float f = (ncoef*mv[l] + bcoef*bv[l]) * inv;
            float c = fminf(f, 1.f - 1e-5f);
            m[lane + l*64] = f2bf(c);
            float s2 = wave_sum(c*c);            // head == l
            if (lane == 0) {
                if (which == 0)
                    qinfo[(size_t)l*Mm + row] = make_float2(2.f*s2, 1.f/(1.f - s2));
                else {
                    float ik = 1.f/(1.f - s2);
                    kinfo[(size_t)l*Mm + row] = make_float2(ik, 2.f*s2*ik);
                }
            }
        }
    } else {
        #pragma unroll
        for (int l = 0; l < 12; ++l)
            m[lane + l*64] = f2bf((ncoef*mv[l] + bcoef*bv[l]) * inv);
    }
}

// ---------------- V transpose (bf16 -> bf16): qkv v-region -> [b,h,d][1024] ----------------
__global__ __launch_bounds__(256) void transpose_v_kernel(const unsigned short* __restrict__ QKV,
                                                          unsigned short* __restrict__ Vb) {
    __shared__ unsigned short t[64][72];
    const int tid = threadIdx.x;
    const int st = blockIdx.x, h = blockIdx.y, b = blockIdx.z;
    {
        int sr = tid >> 2, d0 = (tid & 3) * 16;
        const unsigned short* vp = QKV + ((size_t)b*Ss + st*64 + sr)*LQKV + 2*Ee + h*64 + d0;
        *(s16x8*)&t[sr][d0]     = *(const s16x8*)&vp[0];
        *(s16x8*)&t[sr][d0 + 8] = *(const s16x8*)&vp[8];
    }
    __syncthreads();
    {
        int d = tid >> 2, s0 = (tid & 3) * 16;
        unsigned hu[8];
        #pragma unroll
        for (int i = 0; i < 8; ++i)
            hu[i] = (unsigned)t[s0 + 2*i][d] | ((unsigned)t[s0 + 2*i + 1][d] << 16);
        size_t obase = (((size_t)b*Hh + h)*64 + d)*Ss + st*64 + s0;
        *reinterpret_cast<uint4*>(&Vb[obase])     = make_uint4(hu[0],hu[1],hu[2],hu[3]);
        *reinterpret_cast<uint4*>(&Vb[obase + 8]) = make_uint4(hu[4],hu[5],hu[6],hu[7]);
    }
}

// ---------------- MFMA attention: 128 q-rows/block (32/wave), scalar transform ----------------
__global__ __launch_bounds__(256) void attn_mfma5(
    unsigned short* __restrict__ QKV, const unsigned short* __restrict__ Vb,
    const float2* __restrict__ qinfo, const float2* __restrict__ kinfo,
    const float* __restrict__ hs, float* __restrict__ osq)
{
    __shared__ alignas(16) unsigned short KHs[2][64][64];    // 16KB
    __shared__ alignas(16) unsigned short VHs[2][64][64];    // 16KB
    __shared__ alignas(16) unsigned short PHs[4][2][16][64]; // 16KB
    __shared__ float us[2][64], vs[2][64];                   // 1KB

    const int tid = threadIdx.x, lane = tid & 63, w = tid >> 6;
    const int g = lane >> 4, lg = lane & 15;
    const int qt = blockIdx.x, h = blockIdx.y, b = blockIdx.z;
    const int q0 = qt * 128, hoff = h * 64;
    const size_t rowB = (size_t)b * Ss;
    const size_t hMm = (size_t)h * Mm;
    const size_t vBase = (((size_t)b*Hh + h)*64)*Ss;
    const int rr = tid >> 3, cc = tid & 7;
    const int csw = (cc ^ (rr & 7)) * 8;    // same for rr and rr+32

    const unsigned short* kgp = &QKV[(rowB + rr)*LQKV + Ee + hoff + cc*8];
    const unsigned short* vgp = &Vb[vBase + (size_t)rr*Ss + cc*8];

    // Q fragments + per-q constants (2 row-groups of 16 per wave)
    s16x8 qh[2][2];
    float a2s[2], ioms[2];
    #pragma unroll
    for (int qi = 0; qi < 2; ++qi) {
        const unsigned short* qp = QKV + (rowB + q0 + 32*w + qi*16 + lg)*LQKV + hoff;
        qh[qi][0] = *(const s16x8*)&qp[g*8];
        qh[qi][1] = *(const s16x8*)&qp[32 + g*8];
        float2 qiv = qinfo[hMm + rowB + q0 + 32*w + qi*16 + lg];
        a2s[qi] = qiv.x;
        ioms[qi] = qiv.y;
    }
    const float nia = -1.f / (hs[h] * 8.f);   // p = uu^nia

    s16x8 cka, ckb, cva, cvb, nka, nkb, nva, nvb;
    #define LOADKV(ka,kb,va,vb_,kt) do { \
        ka  = *(const s16x8*)&kgp[(size_t)(kt)*64*LQKV]; \
        kb  = *(const s16x8*)&kgp[(size_t)(kt)*64*LQKV + (size_t)32*LQKV]; \
        va  = *(const s16x8*)&vgp[(kt)*64]; \
        vb_ = *(const s16x8*)&vgp[(size_t)32*Ss + (kt)*64]; } while(0)
    #define WRITEKV(bi,ka,kb,va,vb_) do { \
        *(s16x8*)&KHs[bi][rr     ][csw] = ka; \
        *(s16x8*)&KHs[bi][rr + 32][csw] = kb; \
        *(s16x8*)&VHs[bi][rr     ][csw] = va; \
        *(s16x8*)&VHs[bi][rr + 32][csw] = vb_; } while(0)

    LOADKV(cka,ckb,cva,cvb, 0);
    LOADKV(nka,nkb,nva,nvb, 1);
    float2 uvC = make_float2(0.f,0.f), uvN = make_float2(0.f,0.f);
    if (tid < 64) uvC = kinfo[hMm + rowB + tid];
    if (tid < 64) uvN = kinfo[hMm + rowB + 64 + tid];
    WRITEKV(0, cka,ckb,cva,cvb);
    if (tid < 64) { us[0][tid] = uvC.x; vs[0][tid] = uvC.y; }
    BAR_LGKM();

    f32x4 zero4 = {0.f,0.f,0.f,0.f};
    f32x4 oacc[2][4];
    #pragma unroll
    for (int qi = 0; qi < 2; ++qi)
        #pragma unroll
        for (int i = 0; i < 4; ++i) oacc[qi][i] = zero4;
    float lsum0 = 0.f, lsum1 = 0.f;
    int cur = 0;

    for (int kt = 0; kt < 16; ++kt) {
        if (kt < 15) {
            WRITEKV(cur^1, nka,nkb,nva,nvb);
            if (tid < 64) { us[cur^1][tid] = uvN.x; vs[cur^1][tid] = uvN.y; }
        }
        if (kt < 14) {
            LOADKV(nka,nkb,nva,nvb, kt+2);
            if (tid < 64) uvN = kinfo[hMm + rowB + (kt+2)*64 + tid];
        }

        // ---- S^T tile = K · Q^T (each K-frag feeds 2 q-groups) ----
        f32x4 sacc[2][4];
        #pragma unroll
        for (int qi = 0; qi < 2; ++qi)
            #pragma unroll
            for (int i = 0; i < 4; ++i) sacc[qi][i] = zero4;
        __builtin_amdgcn_s_setprio(1);
        #pragma unroll
        for (int nt = 0; nt < 4; ++nt) {
            const int krow = nt*16 + lg, sw = krow & 7;
            s16x8 kh0 = *(const s16x8*)&KHs[cur][krow][((g    ) ^ sw)*8];
            s16x8 kh1 = *(const s16x8*)&KHs[cur][krow][((4 + g) ^ sw)*8];
            sacc[0][nt] = __builtin_amdgcn_mfma_f32_16x16x32_bf16(kh0, qh[0][0], sacc[0][nt], 0, 0, 0);
            sacc[0][nt] = __builtin_amdgcn_mfma_f32_16x16x32_bf16(kh1, qh[0][1], sacc[0][nt], 0, 0, 0);
            sacc[1][nt] = __builtin_amdgcn_mfma_f32_16x16x32_bf16(kh0, qh[1][0], sacc[1][nt], 0, 0, 0);
            sacc[1][nt] = __builtin_amdgcn_mfma_f32_16x16x32_bf16(kh1, qh[1][1], sacc[1][nt], 0, 0, 0);
        }
        __builtin_amdgcn_s_setprio(0);

        // ---- hyperbolic transform (scalar fp32) -> unnormalized P (bf16) ----
        #pragma unroll
        for (int nt = 0; nt < 4; ++nt) {
            const int j0 = nt*16 + g*4;
            float4 uq4 = *reinterpret_cast<const float4*>(&us[cur][j0]);
            float4 vq4 = *reinterpret_cast<const float4*>(&vs[cur][j0]);
            float uqa[4] = {uq4.x, uq4.y, uq4.z, uq4.w};
            float vqa[4] = {vq4.x, vq4.y, vq4.z, vq4.w};
            const int chq = ((j0 >> 3) ^ (lg & 7))*8 + (j0 & 7);
            #pragma unroll
            for (int qi = 0; qi < 2; ++qi) {
                float pr[4];
                #pragma unroll
                for (int r = 0; r < 4; ++r) {
                    float s  = sacc[qi][nt][r];
                    float wv = fmaf(-4.f, s, a2s[qi]);                  // 2q2 - 4s
                    float z  = fmaf(ioms[qi], fmaf(uqa[r], wv, vqa[r]), 1.f);  // 1 + t
                    z = fmaxf(z, 1.f);
                    float sq = __builtin_amdgcn_sqrtf(fmaf(z, z, -1.f));       // sqrt(z^2-1)
                    float uu = z + sq;                                  // arccosh arg
                    float p  = __builtin_amdgcn_exp2f(nia * __builtin_amdgcn_logf(uu));
                    if (qi == 0) lsum0 += p; else lsum1 += p;
                    pr[r] = p;
                }
                unsigned p01, p23;
                asm("v_cvt_pk_bf16_f32 %0, %1, %2" : "=v"(p01) : "v"(pr[0]), "v"(pr[1]));
                asm("v_cvt_pk_bf16_f32 %0, %1, %2" : "=v"(p23) : "v"(pr[2]), "v"(pr[3]));
                *reinterpret_cast<uint2*>(&PHs[w][qi][lg][chq]) = make_uint2(p01, p23);
            }
        }

        // ---- O += P · V (each V-frag feeds 2 q-groups; P wave-private) ----
        __builtin_amdgcn_s_setprio(1);
        #pragma unroll
        for (int jh = 0; jh < 2; ++jh) {
            s16x8 pa0 = *(const s16x8*)&PHs[w][0][lg][((jh*4 + g) ^ (lg & 7))*8];
            s16x8 pa1 = *(const s16x8*)&PHs[w][1][lg][((jh*4 + g) ^ (lg & 7))*8];
            #pragma unroll
            for (int nt2 = 0; nt2 < 4; ++nt2) {
                const int vrow = nt2*16 + lg;
                s16x8 vh = *(const s16x8*)&VHs[cur][vrow][((jh*4 + g) ^ (vrow & 7))*8];
                oacc[0][nt2] = __builtin_amdgcn_mfma_f32_16x16x32_bf16(pa0, vh, oacc[0][nt2], 0, 0, 0);
                oacc[1][nt2] = __builtin_amdgcn_mfma_f32_16x16x32_bf16(pa1, vh, oacc[1][nt2], 0, 0, 0);
            }
        }
        __builtin_amdgcn_s_setprio(0);

        BAR_LGKM();
        cur ^= 1;
    }
    #undef LOADKV
    #undef WRITEKV

    // ---- normalize, store bf16 O, per-row sumsq ----
    #pragma unroll
    for (int qi = 0; qi < 2; ++qi) {
        float ls = (qi == 0) ? lsum0 : lsum1;
        ls += __shfl_xor(ls, 16);
        ls += __shfl_xor(ls, 32);
        #pragma unroll
        for (int r = 0; r < 4; ++r) {
            float lr = __shfl(ls, g*4 + r, 64);
            float li = 1.f / lr;
            float sq = 0.f;
            const size_t orow = rowB + q0 + 32*w + qi*16 + g*4 + r;
            #pragma unroll
            for (int nt2 = 0; nt2 < 4; ++nt2) {
                float o = oacc[qi][nt2][r] * li;
                sq = fmaf(o, o, sq);
                QKV[orow*LQKV + 2*Ee + hoff + nt2*16 + lg] = f2bf(o);
            }
            sq += __shfl_xor(sq, 1);
            sq += __shfl_xor(sq, 2);
            sq += __shfl_xor(sq, 4);
            sq += __shfl_xor(sq, 8);
            if (lg == 0) osq[hMm + orow] = sq;
        }
    }
}

// ---------------- final mobius fix (wave/row): xn = sqrt(sum_h osq) ----------------
__global__ __launch_bounds__(256) void mobius_fix_final(const float* __restrict__ src,
                                                        float* __restrict__ dst,
                                                        const float* __restrict__ osq,
                                                        const float* __restrict__ bias) {
    const int lane = threadIdx.x & 63, wv = threadIdx.x >> 6;
    size_t row = (size_t)blockIdx.x * 4 + wv;
    const float* m = src + row * Ee;
    float mv[12], bv[12];
    float ss = 0.f;
    #pragma unroll
    for (int l = 0; l < 12; ++l) { mv[l] = m[lane + l*64]; ss += mv[l]*mv[l]; }
    float mxn2 = wave_sum(ss);
    float mxn = fmaxf(sqrtf(mxn2), 1e-15f);
    float ss2 = 0.f;
    #pragma unroll
    for (int hh = 0; hh < Hh; ++hh) ss2 += osq[(size_t)hh*Mm + row];
    float xn = fmaxf(sqrtf(ss2), 1e-15f);
    float xc = fminf(xn, 1.f - 1e-7f);
    float at = 0.5f * logf((1.f + xc) / (1.f - xc));
    float th = tanhf(mxn / xn * at);
    float scale = th / mxn;
    float m2 = th * th;
    float mb = 0.f, b2 = 0.f;
    #pragma unroll
    for (int l = 0; l < 12; ++l) {
        bv[l] = bias[lane + l*64];
        mv[l] *= scale;
        mb += mv[l]*bv[l];
        b2 += bv[l]*bv[l];
    }
    mb = wave_sum(mb);
    b2 = wave_sum(b2);
    float ncoef = 1.f + 2.f*mb + b2;
    float bcoef = 1.f - m2;
    float inv = 1.f / (1.f + 2.f*mb + m2*b2 + 1e-15f);
    float* d = dst + row * Ee;
    #pragma unroll
    for (int l = 0; l < 12; ++l)
        d[lane + l*64] = (ncoef*mv[l] + bcoef*bv[l]) * inv;
}

extern "C" void kernel_launch(void* const* d_in, const int* in_sizes, int n_in,
                              void* d_out, int out_size, void* d_ws, size_t ws_size,
                              hipStream_t stream) {
    const float* x  = (const float*)d_in[0];
    const float* Wq = (const float*)d_in[1];
    const float* bq = (const float*)d_in[2];
    const float* Wk = (const float*)d_in[3];
    const float* bk = (const float*)d_in[4];
    const float* Wv = (const float*)d_in[5];
    const float* bv = (const float*)d_in[6];
    const float* Wo = (const float*)d_in[7];
    const float* bo = (const float*)d_in[8];
    const float* hs = (const float*)d_in[9];
    float* out = (float*)d_out;

    const size_t NE = (size_t)Mm * Ee;
    float* ws    = (float*)d_ws;
    float* xn_x  = ws;                                   // Mm f32
    float* osq   = xn_x + Mm;                            // Hh*Mm f32
    float2* qinfo = (float2*)(osq + (size_t)Hh*Mm);      // Hh*Mm f32x2
    float2* kinfo = qinfo + (size_t)Hh*Mm;               // Hh*Mm f32x2
    unsigned short* qkvbf = (unsigned short*)(kinfo + (size_t)Hh*Mm);  // Mm*2304 u16
    unsigned short* vtbf  = qkvbf + (size_t)Mm * LQKV;   // NE u16
    unsigned short* xbf   = vtbf + NE;                   // NE u16
    unsigned short* wbf   = xbf + NE;                    // 4*NW u16
    float* fbuf = (float*)vtbf;   // fp32 [Mm][768] overlays vtbf+xbf (dead by then)

    pack_xw_kernel<<<Mm/4 + 4*(NW/1024), 256, 0, stream>>>(x, Wq, Wk, Wv, Wo, xbf, xn_x, wbf);

    // fused QKV projection -> bf16 [Mm][2304]
    gemm_bf16_nt<1><<<dim3(Mm/128, LQKV/128), 256, 0, stream>>>(xbf, Ee, wbf, qkvbf, LQKV);
    fix_qkv_kernel<<<dim3(Mm/4, 3), 256, 0, stream>>>(qkvbf, xn_x, bq, bk, bv, qinfo, kinfo);
    transpose_v_kernel<<<dim3(Ss/64, Hh, Bb), 256, 0, stream>>>(qkvbf, vtbf);

    // attention: O (bf16) overwrites V region; osq = per-(head,row) sumsq
    attn_mfma5<<<dim3(Ss/128, Hh, Bb), 256, 0, stream>>>(qkvbf, vtbf, qinfo, kinfo, hs, osq);

    // output projection
    gemm_bf16_nt<0><<<dim3(Mm/128, Ee/128), 256, 0, stream>>>(qkvbf + 2*Ee, LQKV, wbf + 3*(size_t)NW, fbuf, Ee);
    mobius_fix_final<<<Mm/4, 256, 0, stream>>>(fbuf, out, osq, bo);
}

// Round 13
// 176.188 us; speedup vs baseline: 1.2729x; 1.0297x over previous
//
#include <hip/hip_runtime.h>
#include <hip/hip_bf16.h>
#include <math.h>

#define Bb 8
#define Ss 1024
#define Ee 768
#define Hh 12
#define Mm (Bb*Ss)      // 8192 rows
#define NW (Ee*Ee)      // 589824
#define LQKV 2304       // fused QKV row stride (u16 elements)

typedef short  s16x8 __attribute__((ext_vector_type(8)));   // 8 bf16 (4 VGPRs)
typedef float  f32x4 __attribute__((ext_vector_type(4)));

#define FENCE() __builtin_amdgcn_sched_barrier(0)
#define BAR_ONLY() do { FENCE(); __builtin_amdgcn_s_barrier(); FENCE(); } while(0)
#define BAR_LGKM() do { FENCE(); asm volatile("s_waitcnt lgkmcnt(0)" ::: "memory"); FENCE(); \
                        __builtin_amdgcn_s_barrier(); FENCE(); } while(0)

__device__ __forceinline__ unsigned short f2bf(float f) {
    __hip_bfloat16 b = __float2bfloat16(f);   // RNE
    return *reinterpret_cast<unsigned short*>(&b);
}
__device__ __forceinline__ float bf2f(unsigned short h) {
    return __uint_as_float(((unsigned)h) << 16);
}
__device__ __forceinline__ float wave_sum(float v) {
    #pragma unroll
    for (int off = 1; off < 64; off <<= 1) v += __shfl_xor(v, off);
    return v;
}

// ---------------- fused: x->bf16 + row norm (wave/row) | weights->bf16 ----------------
__global__ __launch_bounds__(256) void pack_xw_kernel(const float* __restrict__ x,
    const float* __restrict__ W0, const float* __restrict__ W1,
    const float* __restrict__ W2, const float* __restrict__ W3,
    unsigned short* __restrict__ Xb, float* __restrict__ xn,
    unsigned short* __restrict__ Wb) {
    const int bid = blockIdx.x;
    const int lane = threadIdx.x & 63, wv = threadIdx.x >> 6;
    if (bid < Mm/4) {
        size_t row = (size_t)bid * 4 + wv;
        const float* a = x + row * Ee;
        float ssum = 0.f;
        #pragma unroll
        for (int l = 0; l < 12; ++l) {
            float v = a[lane + l*64];
            ssum += v*v;
            Xb[row*Ee + lane + l*64] = f2bf(v);
        }
        ssum = wave_sum(ssum);
        if (lane == 0) xn[row] = fmaxf(sqrtf(ssum), 1e-15f);
    } else {
        int idx = bid - Mm/4;
        const int perW = NW/1024;          // 576
        int which = idx / perW;
        int chunk = idx - which*perW;
        const float* src = (which == 0) ? W0 : (which == 1) ? W1 : (which == 2) ? W2 : W3;
        size_t off = (size_t)chunk * 1024 + threadIdx.x * 4;
        float4 v = *reinterpret_cast<const float4*>(&src[off]);
        uint2 o;
        o.x = (unsigned)f2bf(v.x) | ((unsigned)f2bf(v.y) << 16);
        o.y = (unsigned)f2bf(v.z) | ((unsigned)f2bf(v.w) << 16);
        *reinterpret_cast<uint2*>(Wb + (size_t)which * NW + off) = o;
    }
}

// ---------------- C[M,N] = A[M,768](bf16,lda) @ B[N,768](bf16)^T ----------------
// BM=128, BN=96, BK=64; 256 threads; reg-staged 2-phase, raw barriers (R8/R11-proven
// structure; BN=96 for exact grid balance: QKV 1536 blk = 6/CU, O-proj 512 = 2/CU).
template<int OUT16>
__global__ __launch_bounds__(256) void gemm_bf16_nt(const unsigned short* __restrict__ A,
                                                    int lda,
                                                    const unsigned short* __restrict__ B,
                                                    void* __restrict__ Cout, int ldc) {
    __shared__ alignas(16) unsigned short As[128][64];   // 16KB, chunk-XOR-swizzled
    __shared__ alignas(16) unsigned short Bs[96][64];    // 12KB
    const int tid = threadIdx.x, lane = tid & 63, w = tid >> 6;
    const int g = lane >> 4, lg = lane & 15;
    const int mBase = blockIdx.x * 128, nBase = blockIdx.y * 96;
    const int wr = w >> 1, wc = w & 1;
    const int rr = tid >> 3, cc = tid & 7;
    const int csw = (cc ^ (rr & 7)) * 8;   // same for rr+32k (32 ≡ 0 mod 8)
    f32x4 zero4 = {0.f,0.f,0.f,0.f};
    f32x4 acc[4][3];
    #pragma unroll
    for (int i = 0; i < 4; ++i)
        #pragma unroll
        for (int j = 0; j < 3; ++j) acc[i][j] = zero4;

    s16x8 av[4], bv[3];
    #define GLOAD(k0) do { \
        _Pragma("unroll") \
        for (int i = 0; i < 4; ++i) \
            av[i] = *(const s16x8*)&A[(size_t)(mBase + rr + i*32)*lda + (k0) + cc*8]; \
        _Pragma("unroll") \
        for (int i = 0; i < 3; ++i) \
            bv[i] = *(const s16x8*)&B[(size_t)(nBase + rr + i*32)*Ee  + (k0) + cc*8]; \
        } while(0)

    GLOAD(0);
    for (int k0 = 0; k0 < Ee; k0 += 64) {
        BAR_ONLY();                        // prev compute consumed its reads pre-barrier
        #pragma unroll
        for (int i = 0; i < 4; ++i) *(s16x8*)&As[rr + i*32][csw] = av[i];
        #pragma unroll
        for (int i = 0; i < 3; ++i) *(s16x8*)&Bs[rr + i*32][csw] = bv[i];
        if (k0 + 64 < Ee) GLOAD(k0 + 64);  // stays in flight across the barrier
        BAR_LGKM();                        // LDS visible; vmcnt NOT drained
        __builtin_amdgcn_s_setprio(1);
        #pragma unroll
        for (int kk = 0; kk < 2; ++kk) {
            s16x8 af[4], bfr[3];
            #pragma unroll
            for (int mi = 0; mi < 4; ++mi) {
                int ar = wr*64 + mi*16 + lg;
                af[mi] = *(const s16x8*)&As[ar][(((kk*4 + g) ^ (ar & 7)))*8];
            }
            #pragma unroll
            for (int ni = 0; ni < 3; ++ni) {
                int br = wc*48 + ni*16 + lg;
                bfr[ni] = *(const s16x8*)&Bs[br][(((kk*4 + g) ^ (br & 7)))*8];
            }
            #pragma unroll
            for (int mi = 0; mi < 4; ++mi)
                #pragma unroll
                for (int ni = 0; ni < 3; ++ni)
                    acc[mi][ni] = __builtin_amdgcn_mfma_f32_16x16x32_bf16(af[mi], bfr[ni], acc[mi][ni], 0, 0, 0);
        }
        __builtin_amdgcn_s_setprio(0);
    }
    #undef GLOAD
    #pragma unroll
    for (int mi = 0; mi < 4; ++mi)
        #pragma unroll
        for (int ni = 0; ni < 3; ++ni)
            #pragma unroll
            for (int r = 0; r < 4; ++r) {
                size_t off = (size_t)(mBase + wr*64 + mi*16 + g*4 + r)*ldc + nBase + wc*48 + ni*16 + lg;
                if (OUT16) ((unsigned short*)Cout)[off] = f2bf(acc[mi][ni][r]);
                else       ((float*)Cout)[off] = acc[mi][ni][r];
            }
}

// ---------------- mobius fix Q/K/V (wave/row, no barriers), in-place bf16 + per-head info ----------------
__global__ __launch_bounds__(256) void fix_qkv_kernel(unsigned short* __restrict__ QKV,
                                                      const float* __restrict__ xn_buf,
                                                      const float* __restrict__ bq,
                                                      const float* __restrict__ bk,
                                                      const float* __restrict__ bv_,
                                                      float2* __restrict__ qinfo,
                                                      float2* __restrict__ kinfo) {
    const int which = blockIdx.y;
    const int lane = threadIdx.x & 63, wv = threadIdx.x >> 6;
    size_t row = (size_t)blockIdx.x * 4 + wv;
    const float* bias = (which == 0) ? bq : (which == 1) ? bk : bv_;
    unsigned short* m = QKV + row * LQKV + which * Ee;
    float mv[12], bv[12];
    float ss = 0.f;
    #pragma unroll
    for (int l = 0; l < 12; ++l) { mv[l] = bf2f(m[lane + l*64]); ss += mv[l]*mv[l]; }
    float mxn2 = wave_sum(ss);
    float mxn = fmaxf(sqrtf(mxn2), 1e-15f);
    float xn = xn_buf[row];
    float xc = fminf(xn, 1.f - 1e-7f);
    float at = 0.5f * logf((1.f + xc) / (1.f - xc));
    float th = tanhf(mxn / xn * at);
    float scale = th / mxn;
    float m2 = th * th;
    float mb = 0.f, b2 = 0.f;
    #pragma unroll
    for (int l = 0; l < 12; ++l) {
        bv[l] = bias[lane + l*64];
        mv[l] *= scale;
        mb += mv[l]*bv[l];
        b2 += bv[l]*bv[l];
    }
    mb = wave_sum(mb);
    b2 = wave_sum(b2);
    float ncoef = 1.f + 2.f*mb + b2;
    float bcoef = 1.f - m2;
    float inv = 1.f / (1.f + 2.f*mb + m2*b2 + 1e-15f);
    if (which < 2) {
        #pragma unroll
        for (int l = 0; l < 12; ++l) {
            float f = (ncoef*mv[l] + bcoef*bv[l]) * inv;
            float c = fminf(f, 1.f - 1e-5f);
            m[lane + l*64] = f2bf(c);
            float s2 = wave_sum(c*c);            // head == l
            if (lane == 0) {
                if (which == 0)
                    qinfo[(size_t)l*Mm + row] = make_float2(2.f*s2, 1.f/(1.f - s2));
                else {
                    float ik = 1.f/(1.f - s2);
                    kinfo[(size_t)l*Mm + row] = make_float2(ik, 2.f*s2*ik);
                }
            }
        }
    } else {
        #pragma unroll
        for (int l = 0; l < 12; ++l)
            m[lane + l*64] = f2bf((ncoef*mv[l] + bcoef*bv[l]) * inv);
    }
}

// ---------------- V transpose (bf16 -> bf16): qkv v-region -> [b,h,d][1024] ----------------
__global__ __launch_bounds__(256) void transpose_v_kernel(const unsigned short* __restrict__ QKV,
                                                          unsigned short* __restrict__ Vb) {
    __shared__ unsigned short t[64][72];
    const int tid = threadIdx.x;
    const int st = blockIdx.x, h = blockIdx.y, b = blockIdx.z;
    {
        int sr = tid >> 2, d0 = (tid & 3) * 16;
        const unsigned short* vp = QKV + ((size_t)b*Ss + st*64 + sr)*LQKV + 2*Ee + h*64 + d0;
        *(s16x8*)&t[sr][d0]     = *(const s16x8*)&vp[0];
        *(s16x8*)&t[sr][d0 + 8] = *(const s16x8*)&vp[8];
    }
    __syncthreads();
    {
        int d = tid >> 2, s0 = (tid & 3) * 16;
        unsigned hu[8];
        #pragma unroll
        for (int i = 0; i < 8; ++i)
            hu[i] = (unsigned)t[s0 + 2*i][d] | ((unsigned)t[s0 + 2*i + 1][d] << 16);
        size_t obase = (((size_t)b*Hh + h)*64 + d)*Ss + st*64 + s0;
        *reinterpret_cast<uint4*>(&Vb[obase])     = make_uint4(hu[0],hu[1],hu[2],hu[3]);
        *reinterpret_cast<uint4*>(&Vb[obase + 8]) = make_uint4(hu[4],hu[5],hu[6],hu[7]);
    }
}

// ---------------- MFMA attention: 128 q-rows/block (32/wave), scalar transform (R11-proven) ----------------
__global__ __launch_bounds__(256) void attn_mfma5(
    unsigned short* __restrict__ QKV, const unsigned short* __restrict__ Vb,
    const float2* __restrict__ qinfo, const float2* __restrict__ kinfo,
    const float* __restrict__ hs, float* __restrict__ osq)
{
    __shared__ alignas(16) unsigned short KHs[2][64][64];    // 16KB
    __shared__ alignas(16) unsigned short VHs[2][64][64];    // 16KB
    __shared__ alignas(16) unsigned short PHs[4][2][16][64]; // 16KB
    __shared__ float us[2][64], vs[2][64];                   // 1KB

    const int tid = threadIdx.x, lane = tid & 63, w = tid >> 6;
    const int g = lane >> 4, lg = lane & 15;
    const int qt = blockIdx.x, h = blockIdx.y, b = blockIdx.z;
    const int q0 = qt * 128, hoff = h * 64;
    const size_t rowB = (size_t)b * Ss;
    const size_t hMm = (size_t)h * Mm;
    const size_t vBase = (((size_t)b*Hh + h)*64)*Ss;
    const int rr = tid >> 3, cc = tid & 7;
    const int csw = (cc ^ (rr & 7)) * 8;    // same for rr and rr+32

    const unsigned short* kgp = &QKV[(rowB + rr)*LQKV + Ee + hoff + cc*8];
    const unsigned short* vgp = &Vb[vBase + (size_t)rr*Ss + cc*8];

    // Q fragments + per-q constants (2 row-groups of 16 per wave)
    s16x8 qh[2][2];
    float a2s[2], ioms[2];
    #pragma unroll
    for (int qi = 0; qi < 2; ++qi) {
        const unsigned short* qp = QKV + (rowB + q0 + 32*w + qi*16 + lg)*LQKV + hoff;
        qh[qi][0] = *(const s16x8*)&qp[g*8];
        qh[qi][1] = *(const s16x8*)&qp[32 + g*8];
        float2 qiv = qinfo[hMm + rowB + q0 + 32*w + qi*16 + lg];
        a2s[qi] = qiv.x;
        ioms[qi] = qiv.y;
    }
    const float nia = -1.f / (hs[h] * 8.f);   // p = uu^nia

    s16x8 cka, ckb, cva, cvb, nka, nkb, nva, nvb;
    #define LOADKV(ka,kb,va,vb_,kt) do { \
        ka  = *(const s16x8*)&kgp[(size_t)(kt)*64*LQKV]; \
        kb  = *(const s16x8*)&kgp[(size_t)(kt)*64*LQKV + (size_t)32*LQKV]; \
        va  = *(const s16x8*)&vgp[(kt)*64]; \
        vb_ = *(const s16x8*)&vgp[(size_t)32*Ss + (kt)*64]; } while(0)
    #define WRITEKV(bi,ka,kb,va,vb_) do { \
        *(s16x8*)&KHs[bi][rr     ][csw] = ka; \
        *(s16x8*)&KHs[bi][rr + 32][csw] = kb; \
        *(s16x8*)&VHs[bi][rr     ][csw] = va; \
        *(s16x8*)&VHs[bi][rr + 32][csw] = vb_; } while(0)

    LOADKV(cka,ckb,cva,cvb, 0);
    LOADKV(nka,nkb,nva,nvb, 1);
    float2 uvC = make_float2(0.f,0.f), uvN = make_float2(0.f,0.f);
    if (tid < 64) uvC = kinfo[hMm + rowB + tid];
    if (tid < 64) uvN = kinfo[hMm + rowB + 64 + tid];
    WRITEKV(0, cka,ckb,cva,cvb);
    if (tid < 64) { us[0][tid] = uvC.x; vs[0][tid] = uvC.y; }
    BAR_LGKM();

    f32x4 zero4 = {0.f,0.f,0.f,0.f};
    f32x4 oacc[2][4];
    #pragma unroll
    for (int qi = 0; qi < 2; ++qi)
        #pragma unroll
        for (int i = 0; i < 4; ++i) oacc[qi][i] = zero4;
    float lsum0 = 0.f, lsum1 = 0.f;
    int cur = 0;

    for (int kt = 0; kt < 16; ++kt) {
        if (kt < 15) {
            WRITEKV(cur^1, nka,nkb,nva,nvb);
            if (tid < 64) { us[cur^1][tid] = uvN.x; vs[cur^1][tid] = uvN.y; }
        }
        if (kt < 14) {
            LOADKV(nka,nkb,nva,nvb, kt+2);
            if (tid < 64) uvN = kinfo[hMm + rowB + (kt+2)*64 + tid];
        }

        // ---- S^T tile = K · Q^T (each K-frag feeds 2 q-groups) ----
        f32x4 sacc[2][4];
        #pragma unroll
        for (int qi = 0; qi < 2; ++qi)
            #pragma unroll
            for (int i = 0; i < 4; ++i) sacc[qi][i] = zero4;
        __builtin_amdgcn_s_setprio(1);
        #pragma unroll
        for (int nt = 0; nt < 4; ++nt) {
            const int krow = nt*16 + lg, sw = krow & 7;
            s16x8 kh0 = *(const s16x8*)&KHs[cur][krow][((g    ) ^ sw)*8];
            s16x8 kh1 = *(const s16x8*)&KHs[cur][krow][((4 + g) ^ sw)*8];
            sacc[0][nt] = __builtin_amdgcn_mfma_f32_16x16x32_bf16(kh0, qh[0][0], sacc[0][nt], 0, 0, 0);
            sacc[0][nt] = __builtin_amdgcn_mfma_f32_16x16x32_bf16(kh1, qh[0][1], sacc[0][nt], 0, 0, 0);
            sacc[1][nt] = __builtin_amdgcn_mfma_f32_16x16x32_bf16(kh0, qh[1][0], sacc[1][nt], 0, 0, 0);
            sacc[1][nt] = __builtin_amdgcn_mfma_f32_16x16x32_bf16(kh1, qh[1][1], sacc[1][nt], 0, 0, 0);
        }
        __builtin_amdgcn_s_setprio(0);

        // ---- hyperbolic transform (scalar fp32) -> unnormalized P (bf16) ----
        #pragma unroll
        for (int nt = 0; nt < 4; ++nt) {
            const int j0 = nt*16 + g*4;
            float4 uq4 = *reinterpret_cast<const float4*>(&us[cur][j0]);
            float4 vq4 = *reinterpret_cast<const float4*>(&vs[cur][j0]);
            float uqa[4] = {uq4.x, uq4.y, uq4.z, uq4.w};
            float vqa[4] = {vq4.x, vq4.y, vq4.z, vq4.w};
            const int chq = ((j0 >> 3) ^ (lg & 7))*8 + (j0 & 7);
            #pragma unroll
            for (int qi = 0; qi < 2; ++qi) {
                float pr[4];
                #pragma unroll
                for (int r = 0; r < 4; ++r) {
                    float s  = sacc[qi][nt][r];
                    float wv = fmaf(-4.f, s, a2s[qi]);                  // 2q2 - 4s
                    float z  = fmaf(ioms[qi], fmaf(uqa[r], wv, vqa[r]), 1.f);  // 1 + t
                    z = fmaxf(z, 1.f);
                    float sq = __builtin_amdgcn_sqrtf(fmaf(z, z, -1.f));       // sqrt(z^2-1)
                    float uu = z + sq;                                  // arccosh arg
                    float p  = __builtin_amdgcn_exp2f(nia * __builtin_amdgcn_logf(uu));
                    if (qi == 0) lsum0 += p; else lsum1 += p;
                    pr[r] = p;
                }
                unsigned p01, p23;
                asm("v_cvt_pk_bf16_f32 %0, %1, %2" : "=v"(p01) : "v"(pr[0]), "v"(pr[1]));
                asm("v_cvt_pk_bf16_f32 %0, %1, %2" : "=v"(p23) : "v"(pr[2]), "v"(pr[3]));
                *reinterpret_cast<uint2*>(&PHs[w][qi][lg][chq]) = make_uint2(p01, p23);
            }
        }

        // ---- O += P · V (each V-frag feeds 2 q-groups; P wave-private) ----
        __builtin_amdgcn_s_setprio(1);
        #pragma unroll
        for (int jh = 0; jh < 2; ++jh) {
            s16x8 pa0 = *(const s16x8*)&PHs[w][0][lg][((jh*4 + g) ^ (lg & 7))*8];
            s16x8 pa1 = *(const s16x8*)&PHs[w][1][lg][((jh*4 + g) ^ (lg & 7))*8];
            #pragma unroll
            for (int nt2 = 0; nt2 < 4; ++nt2) {
                const int vrow = nt2*16 + lg;
                s16x8 vh = *(const s16x8*)&VHs[cur][vrow][((jh*4 + g) ^ (vrow & 7))*8];
                oacc[0][nt2] = __builtin_amdgcn_mfma_f32_16x16x32_bf16(pa0, vh, oacc[0][nt2], 0, 0, 0);
                oacc[1][nt2] = __builtin_amdgcn_mfma_f32_16x16x32_bf16(pa1, vh, oacc[1][nt2], 0, 0, 0);
            }
        }
        __builtin_amdgcn_s_setprio(0);

        BAR_LGKM();
        cur ^= 1;
    }
    #undef LOADKV
    #undef WRITEKV

    // ---- normalize, store bf16 O, per-row sumsq ----
    #pragma unroll
    for (int qi = 0; qi < 2; ++qi) {
        float ls = (qi == 0) ? lsum0 : lsum1;
        ls += __shfl_xor(ls, 16);
        ls += __shfl_xor(ls, 32);
        #pragma unroll
        for (int r = 0; r < 4; ++r) {
            float lr = __shfl(ls, g*4 + r, 64);
            float li = 1.f / lr;
            float sq = 0.f;
            const size_t orow = rowB + q0 + 32*w + qi*16 + g*4 + r;
            #pragma unroll
            for (int nt2 = 0; nt2 < 4; ++nt2) {
                float o = oacc[qi][nt2][r] * li;
                sq = fmaf(o, o, sq);
                QKV[orow*LQKV + 2*Ee + hoff + nt2*16 + lg] = f2bf(o);
            }
            sq += __shfl_xor(sq, 1);
            sq += __shfl_xor(sq, 2);
            sq += __shfl_xor(sq, 4);
            sq += __shfl_xor(sq, 8);
            if (lg == 0) osq[hMm + orow] = sq;
        }
    }
}

// ---------------- final mobius fix (wave/row): xn = sqrt(sum_h osq) ----------------
__global__ __launch_bounds__(256) void mobius_fix_final(const float* __restrict__ src,
                                                        float* __restrict__ dst,
                                                        const float* __restrict__ osq,
                                                        const float* __restrict__ bias) {
    const int lane = threadIdx.x & 63, wv = threadIdx.x >> 6;
    size_t row = (size_t)blockIdx.x * 4 + wv;
    const float* m = src + row * Ee;
    float mv[12], bv[12];
    float ss = 0.f;
    #pragma unroll
    for (int l = 0; l < 12; ++l) { mv[l] = m[lane + l*64]; ss += mv[l]*mv[l]; }
    float mxn2 = wave_sum(ss);
    float mxn = fmaxf(sqrtf(mxn2), 1e-15f);
    float ss2 = 0.f;
    #pragma unroll
    for (int hh = 0; hh < Hh; ++hh) ss2 += osq[(size_t)hh*Mm + row];
    float xn = fmaxf(sqrtf(ss2), 1e-15f);
    float xc = fminf(xn, 1.f - 1e-7f);
    float at = 0.5f * logf((1.f + xc) / (1.f - xc));
    float th = tanhf(mxn / xn * at);
    float scale = th / mxn;
    float m2 = th * th;
    float mb = 0.f, b2 = 0.f;
    #pragma unroll
    for (int l = 0; l < 12; ++l) {
        bv[l] = bias[lane + l*64];
        mv[l] *= scale;
        mb += mv[l]*bv[l];
        b2 += bv[l]*bv[l];
    }
    mb = wave_sum(mb);
    b2 = wave_sum(b2);
    float ncoef = 1.f + 2.f*mb + b2;
    float bcoef = 1.f - m2;
    float inv = 1.f / (1.f + 2.f*mb + m2*b2 + 1e-15f);
    float* d = dst + row * Ee;
    #pragma unroll
    for (int l = 0; l < 12; ++l)
        d[lane + l*64] = (ncoef*mv[l] + bcoef*bv[l]) * inv;
}

extern "C" void kernel_launch(void* const* d_in, const int* in_sizes, int n_in,
                              void* d_out, int out_size, void* d_ws, size_t ws_size,
                              hipStream_t stream) {
    const float* x  = (const float*)d_in[0];
    const float* Wq = (const float*)d_in[1];
    const float* bq = (const float*)d_in[2];
    const float* Wk = (const float*)d_in[3];
    const float* bk = (const float*)d_in[4];
    const float* Wv = (const float*)d_in[5];
    const float* bv = (const float*)d_in[6];
    const float* Wo = (const float*)d_in[7];
    const float* bo = (const float*)d_in[8];
    const float* hs = (const float*)d_in[9];
    float* out = (float*)d_out;

    const size_t NE = (size_t)Mm * Ee;
    float* ws    = (float*)d_ws;
    float* xn_x  = ws;                                   // Mm f32
    float* osq   = xn_x + Mm;                            // Hh*Mm f32
    float2* qinfo = (float2*)(osq + (size_t)Hh*Mm);      // Hh*Mm f32x2
    float2* kinfo = qinfo + (size_t)Hh*Mm;               // Hh*Mm f32x2
    unsigned short* qkvbf = (unsigned short*)(kinfo + (size_t)Hh*Mm);  // Mm*2304 u16
    unsigned short* vtbf  = qkvbf + (size_t)Mm * LQKV;   // NE u16
    unsigned short* xbf   = vtbf + NE;                   // NE u16
    unsigned short* wbf   = xbf + NE;                    // 4*NW u16
    float* fbuf = (float*)vtbf;   // fp32 [Mm][768] overlays vtbf+xbf (dead by then)

    pack_xw_kernel<<<Mm/4 + 4*(NW/1024), 256, 0, stream>>>(x, Wq, Wk, Wv, Wo, xbf, xn_x, wbf);

    // fused QKV projection -> bf16 [Mm][2304]; grid (64,24)=1536 blocks = 6/CU exact
    gemm_bf16_nt<1><<<dim3(Mm/128, LQKV/96), 256, 0, stream>>>(xbf, Ee, wbf, qkvbf, LQKV);
    fix_qkv_kernel<<<dim3(Mm/4, 3), 256, 0, stream>>>(qkvbf, xn_x, bq, bk, bv, qinfo, kinfo);
    transpose_v_kernel<<<dim3(Ss/64, Hh, Bb), 256, 0, stream>>>(qkvbf, vtbf);

    // attention: O (bf16) overwrites V region; osq = per-(head,row) sumsq
    attn_mfma5<<<dim3(Ss/128, Hh, Bb), 256, 0, stream>>>(qkvbf, vtbf, qinfo, kinfo, hs, osq);

    // output projection; grid (64,8)=512 blocks = 2/CU exact
    gemm_bf16_nt<0><<<dim3(Mm/128, Ee/96), 256, 0, stream>>>(qkvbf + 2*Ee, LQKV, wbf + 3*(size_t)NW, fbuf, Ee);
    mobius_fix_final<<<Mm/4, 256, 0, stream>>>(fbuf, out, osq, bo);
}